// Round 1
// baseline (179.212 us; speedup 1.0000x reference)
//
#include <hip/hip_runtime.h>
#include <hip/hip_bf16.h>
#include <stdint.h>

typedef unsigned short u16;
typedef __attribute__((ext_vector_type(8))) short bf16x8;
typedef __attribute__((ext_vector_type(4))) short bf16x4;
typedef __attribute__((ext_vector_type(4))) float f32x4;
typedef __attribute__((ext_vector_type(4))) unsigned int u32x4;

#define BATCH 8
#define NTOK 4096
#define NT 128   // 4096 / 32 t2-tiles

#if __has_builtin(__builtin_amdgcn_exp2f)
#define EXP2F __builtin_amdgcn_exp2f
#else
#define EXP2F exp2f
#endif

__device__ __forceinline__ u16 f2bf(float f) {
    __hip_bfloat16 h = __float2bfloat16(f);
    return *reinterpret_cast<u16*>(&h);
}
__device__ __forceinline__ float bf2f(u16 u) {
    __hip_bfloat16 h = *reinterpret_cast<__hip_bfloat16*>(&u);
    return __bfloat162float(h);
}

__device__ __forceinline__ f32x4 MFMA(bf16x8 a, bf16x8 b, f32x4 c) {
    return __builtin_amdgcn_mfma_f32_16x16x32_bf16(a, b, c, 0, 0, 0);
}

__device__ __forceinline__ void async_copy16(void* lds_dst, const void* g_src) {
    __builtin_amdgcn_global_load_lds(
        (const __attribute__((address_space(1))) uint32_t*)g_src,
        (__attribute__((address_space(3))) uint32_t*)lds_dst, 16, 0, 0);
}

// ---------------------------------------------------------------------------
// k1: QKV projection (fp32) + bf16 hi/lo split + layout packing.
// grid 512 (= 8 batches x 8 token-groups... actually 8 x 64-token blocks),
// block 256 = 64 tokens x 4 o-subranges (48 outputs each).
// Q layout: [b][t][c] bf16 hi/lo, Q pre-scaled by 0.125*log2(e).
// K layout: [b][t][c] bf16 hi/lo with 16B-chunk XOR swizzle: chunk g stored at g^(t&7).
// V layout: pre-packed PV-B-fragment order: [b][T][cb][g2][lane][4 bf16].
// ---------------------------------------------------------------------------
__global__ __launch_bounds__(256) void k_qkv(
    const float* __restrict__ x, const float* __restrict__ wqkv, const float* __restrict__ bqkv,
    u16* __restrict__ Qh, u16* __restrict__ Ql,
    u16* __restrict__ Kh, u16* __restrict__ Kl,
    u16* __restrict__ Vp)
{
    __shared__ uint32_t vlds[64 * 33];   // 64 rows x 66 shorts (pad -> conflict-free column writes)
    const int blk  = blockIdx.x;
    const int b    = blk >> 6;
    const int tbase = (blk & 63) << 6;
    const int tid  = threadIdx.x;
    const int tl   = tid & 63;
    const int osub = __builtin_amdgcn_readfirstlane(tid >> 6);
    const int t    = tbase + tl;

    float xc[64];
#pragma unroll
    for (int c = 0; c < 64; ++c)
        xc[c] = x[(size_t)(b * 64 + c) * NTOK + t];

    const float SC = 0.18033688011112042f;  // (1/8) * log2(e)

#pragma unroll
    for (int ch = 0; ch < 6; ++ch) {
        const int o0 = osub * 48 + ch * 8;
        const int arr = o0 >> 6;            // 0=Q, 1=K, 2=V
        float a[8];
#pragma unroll
        for (int j = 0; j < 8; ++j) {
            const int o = o0 + j;
            float acc = bqkv[o];
            const float* wr = wqkv + o * 64;   // uniform per wave -> scalar loads
#pragma unroll
            for (int c = 0; c < 64; ++c) acc = fmaf(wr[c], xc[c], acc);
            a[j] = acc;
        }
        if (arr == 0) {
#pragma unroll
            for (int j = 0; j < 8; ++j) a[j] *= SC;
        }
        u16 h[8], lo[8];
#pragma unroll
        for (int j = 0; j < 8; ++j) {
            h[j]  = f2bf(a[j]);
            lo[j] = f2bf(a[j] - bf2f(h[j]));
        }
        if (arr < 2) {
            u32x4 H, L;
#pragma unroll
            for (int j = 0; j < 4; ++j) {
                H[j] = (uint32_t)h[2*j]  | ((uint32_t)h[2*j+1]  << 16);
                L[j] = (uint32_t)lo[2*j] | ((uint32_t)lo[2*j+1] << 16);
            }
            const int gch = (o0 & 63) >> 3;
            if (arr == 0) {
                size_t base = ((size_t)(b * NTOK + t)) * 64 + gch * 8;
                *(u32x4*)(Qh + base) = H;
                *(u32x4*)(Ql + base) = L;
            } else {
                const int gs = gch ^ (t & 7);
                size_t base = ((size_t)(b * NTOK + t)) * 64 + gs * 8;
                *(u32x4*)(Kh + base) = H;
                *(u32x4*)(Kl + base) = L;
            }
        } else {
            // V -> LDS rows (stride 33 uints = 66 shorts)
#pragma unroll
            for (int j = 0; j < 4; ++j)
                vlds[tl * 33 + ((o0 & 63) >> 1) + j] =
                    (uint32_t)h[2*j] | ((uint32_t)h[2*j+1] << 16);
        }
    }
    __syncthreads();

    // pack V fragments: unit (b,T,cb,g2,l) elem jj = V[t2loc=(l>>4)*4+jj+16*g2][c=cb*16+(l&15)]
    const u16* vl16 = (const u16*)vlds;
    const int Tb = tbase >> 5;
#pragma unroll
    for (int k = 0; k < 2; ++k) {
        const int lu   = tid * 4 + k * 2;
        const int l    = lu & 63;
        const int g2   = (lu >> 6) & 1;
        const int cb   = (lu >> 7) & 3;
        const int Tloc = lu >> 9;
        u32x4 wvv;
#pragma unroll
        for (int uu = 0; uu < 2; ++uu) {
            const int ll   = l + uu;
            const int rowb = Tloc * 32 + ((ll >> 4) << 2) + (g2 << 4);
            const int col  = (cb << 4) + (ll & 15);
            u16 e0 = vl16[(rowb + 0) * 66 + col];
            u16 e1 = vl16[(rowb + 1) * 66 + col];
            u16 e2 = vl16[(rowb + 2) * 66 + col];
            u16 e3 = vl16[(rowb + 3) * 66 + col];
            wvv[uu*2+0] = (uint32_t)e0 | ((uint32_t)e1 << 16);
            wvv[uu*2+1] = (uint32_t)e2 | ((uint32_t)e3 << 16);
        }
        size_t ubase = ((((size_t)(b * NT + Tb + Tloc) * 4 + cb) * 2 + g2) * 64 + l) * 4;
        *(u32x4*)(Vp + ubase) = wvv;
    }
}

// ---------------------------------------------------------------------------
// k3: flash attention. grid 512 (8 batches x 64 Q-tiles, XCD-swizzled so each
// batch pins to one XCD's L2), block 256 = 4 waves x 16 Q-rows.
// Swapped QK^T: S^T = mfma(A=K, B=Q); hi/lo split: Kh*Qh + Kh*Ql + Kl*Qh.
// ---------------------------------------------------------------------------
__global__ __launch_bounds__(256, 2) void k_attn(
    const u16* __restrict__ Qh, const u16* __restrict__ Ql,
    const u16* __restrict__ Kh, const u16* __restrict__ Kl,
    const u16* __restrict__ Vp, float* __restrict__ O)
{
    __shared__ __align__(16) char lds[24576];  // 2 x (Kh 4K | Kl 4K | Vp 4K)
    const int hw  = blockIdx.x;
    const int b   = hw & 7;        // XCD swizzle: batch = hw%8 -> one XCD per batch
    const int qt  = hw >> 3;       // 0..63
    const int tid = threadIdx.x;
    const int lane = tid & 63;
    const int wv  = tid >> 6;
    const int r   = lane & 15;
    const int g   = lane >> 4;

    // Q fragments (B operand): lane holds Q[t1 = base+r][c = g*8+j (+32*ks)]
    const int t1 = qt * 64 + wv * 16 + r;
    const size_t qoff = ((size_t)(b * NTOK + t1)) * 64 + g * 8;
    const bf16x8 qh0 = *(const bf16x8*)(Qh + qoff);
    const bf16x8 qh1 = *(const bf16x8*)(Qh + qoff + 32);
    const bf16x8 ql0 = *(const bf16x8*)(Ql + qoff);
    const bf16x8 ql1 = *(const bf16x8*)(Ql + qoff + 32);

    // iter-invariant LDS byte offsets for K frags (chunk-XOR deswizzle)
    int koff[2][2];
#pragma unroll
    for (int st = 0; st < 2; ++st)
#pragma unroll
        for (int ks = 0; ks < 2; ++ks)
            koff[st][ks] = (st*16 + r) * 128 + (((g + 4*ks) ^ (r & 7)) << 4);

    const char* gKh = (const char*)(Kh + (size_t)b * NTOK * 64);
    const char* gKl = (const char*)(Kl + (size_t)b * NTOK * 64);
    const char* gVp = (const char*)(Vp + (size_t)b * NT * 2048);

    auto stage = [&](int T, int buf) {
        char* dst = lds + buf * 12288 + tid * 16;
        async_copy16(dst,        gKh + (size_t)T * 4096 + tid * 16);
        async_copy16(dst + 4096, gKl + (size_t)T * 4096 + tid * 16);
        async_copy16(dst + 8192, gVp + (size_t)T * 4096 + tid * 16);
    };

    f32x4 oacc[4];
#pragma unroll
    for (int i = 0; i < 4; ++i) oacc[i] = 0.f;
    float mrun = -1e30f, lrun = 0.f;

    stage(0, 0);
    asm volatile("s_waitcnt vmcnt(0)" ::: "memory");
    __syncthreads();
    int cur = 0;

    for (int T = 0; T < NT; ++T) {
        if (T + 1 < NT) stage(T + 1, cur ^ 1);

        const char* kb = lds + cur * 12288;
        const char* klb = kb + 4096;
        const char* vb  = kb + 8192;

        const bf16x8 kh00 = *(const bf16x8*)(kb  + koff[0][0]);
        const bf16x8 kh01 = *(const bf16x8*)(kb  + koff[0][1]);
        const bf16x8 kh10 = *(const bf16x8*)(kb  + koff[1][0]);
        const bf16x8 kh11 = *(const bf16x8*)(kb  + koff[1][1]);
        const bf16x8 kl00 = *(const bf16x8*)(klb + koff[0][0]);
        const bf16x8 kl01 = *(const bf16x8*)(klb + koff[0][1]);
        const bf16x8 kl10 = *(const bf16x8*)(klb + koff[1][0]);
        const bf16x8 kl11 = *(const bf16x8*)(klb + koff[1][1]);

        bf16x8 vf[4];
#pragma unroll
        for (int cb = 0; cb < 4; ++cb) {
            bf16x4 lo4 = *(const bf16x4*)(vb + ((cb*2+0)*64 + lane)*8);
            bf16x4 hi4 = *(const bf16x4*)(vb + ((cb*2+1)*64 + lane)*8);
            vf[cb] = __builtin_shufflevector(lo4, hi4, 0,1,2,3,4,5,6,7);
        }

        f32x4 s0 = 0.f, s1 = 0.f;
        s0 = MFMA(kh00, qh0, s0); s0 = MFMA(kh01, qh1, s0);
        s0 = MFMA(kh00, ql0, s0); s0 = MFMA(kh01, ql1, s0);
        s0 = MFMA(kl00, qh0, s0); s0 = MFMA(kl01, qh1, s0);
        s1 = MFMA(kh10, qh0, s1); s1 = MFMA(kh11, qh1, s1);
        s1 = MFMA(kh10, ql0, s1); s1 = MFMA(kh11, ql1, s1);
        s1 = MFMA(kl10, qh0, s1); s1 = MFMA(kl11, qh1, s1);

        // wave-parallel online softmax (row t1 = r; 4 lane-groups hold different t2)
        float sm[8] = {s0[0],s0[1],s0[2],s0[3], s1[0],s1[1],s1[2],s1[3]};
        float m8 = fmaxf(fmaxf(fmaxf(sm[0],sm[1]), fmaxf(sm[2],sm[3])),
                         fmaxf(fmaxf(sm[4],sm[5]), fmaxf(sm[6],sm[7])));
        m8 = fmaxf(m8, __shfl_xor(m8, 16));
        m8 = fmaxf(m8, __shfl_xor(m8, 32));
        const float mnew = fmaxf(mrun, m8);
        const float corr = EXP2F(mrun - mnew);
        float p[8];
        float ls = 0.f;
#pragma unroll
        for (int i = 0; i < 8; ++i) { p[i] = EXP2F(sm[i] - mnew); ls += p[i]; }
        ls += __shfl_xor(ls, 16);
        ls += __shfl_xor(ls, 32);
        lrun = lrun * corr + ls;
        mrun = mnew;

        // redistribute corr from softmax layout (t1=r) to O-accum layout (t1=g*4+reg)
        float c4[4];
#pragma unroll
        for (int i = 0; i < 4; ++i) c4[i] = __shfl(corr, g * 4 + i);
#pragma unroll
        for (int cb = 0; cb < 4; ++cb)
#pragma unroll
            for (int i = 0; i < 4; ++i) oacc[cb][i] *= c4[i];

        bf16x8 pa;
#pragma unroll
        for (int i = 0; i < 8; ++i) pa[i] = (short)f2bf(p[i]);

#pragma unroll
        for (int cb = 0; cb < 4; ++cb)
            oacc[cb] = MFMA(pa, vf[cb], oacc[cb]);

        asm volatile("s_waitcnt vmcnt(0)" ::: "memory");
        __syncthreads();
        cur ^= 1;
    }

    const float inv = 1.0f / lrun;
    float i4[4];
#pragma unroll
    for (int i = 0; i < 4; ++i) i4[i] = __shfl(inv, g * 4 + i);
#pragma unroll
    for (int cb = 0; cb < 4; ++cb)
#pragma unroll
        for (int i = 0; i < 4; ++i) {
            const int trow = qt * 64 + wv * 16 + g * 4 + i;
            O[((size_t)(b * NTOK + trow)) * 64 + cb * 16 + r] = oacc[cb][i] * i4[i];
        }
}

// ---------------------------------------------------------------------------
// k4: out projection (fp32) + residual.
// ---------------------------------------------------------------------------
__global__ __launch_bounds__(256) void k_out(
    const float* __restrict__ O, const float* __restrict__ wout, const float* __restrict__ bout,
    const float* __restrict__ x, float* __restrict__ out)
{
    const int blk  = blockIdx.x;
    const int b    = blk >> 6;
    const int tbase = (blk & 63) << 6;
    const int tid  = threadIdx.x;
    const int tl   = tid & 63;
    const int osub = __builtin_amdgcn_readfirstlane(tid >> 6);
    const int t    = tbase + tl;

    float y[64];
    const float* orow = O + ((size_t)(b * NTOK + t)) * 64;
#pragma unroll
    for (int c4 = 0; c4 < 16; ++c4) {
        f32x4 v = *(const f32x4*)(orow + c4 * 4);
        y[c4*4+0] = v[0]; y[c4*4+1] = v[1]; y[c4*4+2] = v[2]; y[c4*4+3] = v[3];
    }
#pragma unroll
    for (int i = 0; i < 16; ++i) {
        const int o = osub * 16 + i;
        float acc = bout[o];
        const float* wr = wout + o * 64;   // uniform per wave -> scalar loads
#pragma unroll
        for (int c = 0; c < 64; ++c) acc = fmaf(wr[c], y[c], acc);
        const size_t xi = (size_t)(b * 64 + o) * NTOK + t;
        out[xi] = acc + x[xi];
    }
}

extern "C" void kernel_launch(void* const* d_in, const int* in_sizes, int n_in,
                              void* d_out, int out_size, void* d_ws, size_t ws_size,
                              hipStream_t stream)
{
    (void)in_sizes; (void)n_in; (void)out_size; (void)ws_size;
    const float* x    = (const float*)d_in[0];
    const float* wqkv = (const float*)d_in[1];
    const float* bqkv = (const float*)d_in[2];
    const float* wout = (const float*)d_in[3];
    const float* bout = (const float*)d_in[4];
    float* out = (float*)d_out;

    char* ws = (char*)d_ws;
    const size_t MB = 1024 * 1024;
    u16* Qh = (u16*)(ws);
    u16* Ql = (u16*)(ws + 4 * MB);
    u16* Kh = (u16*)(ws + 8 * MB);
    u16* Kl = (u16*)(ws + 12 * MB);
    u16* Vp = (u16*)(ws + 16 * MB);
    float* Ob = (float*)(ws + 20 * MB);

    k_qkv<<<512, 256, 0, stream>>>(x, wqkv, bqkv, Qh, Ql, Kh, Kl, Vp);
    k_attn<<<512, 256, 0, stream>>>(Qh, Ql, Kh, Kl, Vp, Ob);
    k_out<<<512, 256, 0, stream>>>(Ob, wout, bout, x, out);
}

// Round 2
// 141.251 us; speedup vs baseline: 1.2688x; 1.2688x over previous
//
#include <hip/hip_runtime.h>
#include <hip/hip_bf16.h>
#include <stdint.h>

typedef unsigned short u16;
typedef __attribute__((ext_vector_type(8))) short bf16x8;
typedef __attribute__((ext_vector_type(4))) short bf16x4;
typedef __attribute__((ext_vector_type(4))) float f32x4;
typedef __attribute__((ext_vector_type(4))) unsigned int u32x4;

#define BATCH 8
#define NTOK 4096
#define NT64 64   // 4096 / 64 t2-tiles

#if __has_builtin(__builtin_amdgcn_exp2f)
#define EXP2F __builtin_amdgcn_exp2f
#else
#define EXP2F exp2f
#endif

__device__ __forceinline__ u16 f2bf(float f) {
    __hip_bfloat16 h = __float2bfloat16(f);
    return *reinterpret_cast<u16*>(&h);
}
__device__ __forceinline__ float bf2f(u16 u) {
    __hip_bfloat16 h = *reinterpret_cast<__hip_bfloat16*>(&u);
    return __bfloat162float(h);
}

__device__ __forceinline__ f32x4 MFMA(bf16x8 a, bf16x8 b, f32x4 c) {
    return __builtin_amdgcn_mfma_f32_16x16x32_bf16(a, b, c, 0, 0, 0);
}

__device__ __forceinline__ void async_copy16(void* lds_dst, const void* g_src) {
    __builtin_amdgcn_global_load_lds(
        (const __attribute__((address_space(1))) uint32_t*)g_src,
        (__attribute__((address_space(3))) uint32_t*)lds_dst, 16, 0, 0);
}

// ---------------------------------------------------------------------------
// k1: QKV projection (fp32) + bf16 hi/lo split + layout packing.
// grid 512 (8 batches x 64-token blocks), block 256 = 64 tokens x 4 o-subranges.
// Q layout: [b][t][c] bf16 hi/lo, Q pre-scaled by 0.125*log2(e).
// K layout: [b][t][c] bf16 hi/lo with 16B-chunk XOR swizzle: chunk g at g^(t&7).
// V layout: PV-B-fragment order per 64-token tile: [b][T64][cb][kb][lane][8 bf16]
//   where elem j of unit (cb,kb,l) = V[t2loc = kb*32 + (j>>2)*16 + (l>>4)*4 + (j&3)]
//                                      [c = cb*16 + (l&15)]
// ---------------------------------------------------------------------------
__global__ __launch_bounds__(256) void k_qkv(
    const float* __restrict__ x, const float* __restrict__ wqkv, const float* __restrict__ bqkv,
    u16* __restrict__ Qh, u16* __restrict__ Ql,
    u16* __restrict__ Kh, u16* __restrict__ Kl,
    u16* __restrict__ Vp)
{
    __shared__ uint32_t vlds[64 * 33];   // 64 rows x 66 shorts
    const int blk  = blockIdx.x;
    const int b    = blk >> 6;
    const int tbase = (blk & 63) << 6;
    const int tid  = threadIdx.x;
    const int tl   = tid & 63;
    const int osub = __builtin_amdgcn_readfirstlane(tid >> 6);
    const int t    = tbase + tl;

    float xc[64];
#pragma unroll
    for (int c = 0; c < 64; ++c)
        xc[c] = x[(size_t)(b * 64 + c) * NTOK + t];

    const float SC = 0.18033688011112042f;  // (1/8) * log2(e)

#pragma unroll
    for (int ch = 0; ch < 6; ++ch) {
        const int o0 = osub * 48 + ch * 8;
        const int arr = o0 >> 6;            // 0=Q, 1=K, 2=V
        float a[8];
#pragma unroll
        for (int j = 0; j < 8; ++j) {
            const int o = o0 + j;
            float acc = bqkv[o];
            const float* wr = wqkv + o * 64;   // uniform per wave -> scalar loads
#pragma unroll
            for (int c = 0; c < 64; ++c) acc = fmaf(wr[c], xc[c], acc);
            a[j] = acc;
        }
        if (arr == 0) {
#pragma unroll
            for (int j = 0; j < 8; ++j) a[j] *= SC;
        }
        u16 h[8], lo[8];
#pragma unroll
        for (int j = 0; j < 8; ++j) {
            h[j]  = f2bf(a[j]);
            lo[j] = f2bf(a[j] - bf2f(h[j]));
        }
        if (arr < 2) {
            u32x4 H, L;
#pragma unroll
            for (int j = 0; j < 4; ++j) {
                H[j] = (uint32_t)h[2*j]  | ((uint32_t)h[2*j+1]  << 16);
                L[j] = (uint32_t)lo[2*j] | ((uint32_t)lo[2*j+1] << 16);
            }
            const int gch = (o0 & 63) >> 3;
            if (arr == 0) {
                size_t base = ((size_t)(b * NTOK + t)) * 64 + gch * 8;
                *(u32x4*)(Qh + base) = H;
                *(u32x4*)(Ql + base) = L;
            } else {
                const int gs = gch ^ (t & 7);
                size_t base = ((size_t)(b * NTOK + t)) * 64 + gs * 8;
                *(u32x4*)(Kh + base) = H;
                *(u32x4*)(Kl + base) = L;
            }
        } else {
#pragma unroll
            for (int j = 0; j < 4; ++j)
                vlds[tl * 33 + ((o0 & 63) >> 1) + j] =
                    (uint32_t)h[2*j] | ((uint32_t)h[2*j+1] << 16);
        }
    }
    __syncthreads();

    // pack V fragments for the 64-token tile
    const u16* vl16 = (const u16*)vlds;
    const int Tb = blk & 63;
#pragma unroll
    for (int k = 0; k < 2; ++k) {
        const int idx = tid * 2 + k;        // 0..511 = (cb*2 + kb)*64 + l
        const int l   = idx & 63;
        const int kb  = (idx >> 6) & 1;
        const int cb  = idx >> 7;
        const int rb  = kb * 32 + ((l >> 4) << 2);
        const int col = (cb << 4) + (l & 15);
        u16 e[8];
#pragma unroll
        for (int j = 0; j < 8; ++j)
            e[j] = vl16[(rb + (j & 3) + ((j >> 2) << 4)) * 66 + col];
        u32x4 wvv;
#pragma unroll
        for (int j = 0; j < 4; ++j)
            wvv[j] = (uint32_t)e[2*j] | ((uint32_t)e[2*j+1] << 16);
        *(u32x4*)(Vp + ((size_t)(b * NT64 + Tb) * 512 + idx) * 8) = wvv;
    }
}

// ---------------------------------------------------------------------------
// k3: flash attention. grid 512 (8 batches x 64 Q-tiles of 64 rows), block 256
// = 4 waves = 2 Q-groups (32 rows each) x 2 t2-groups (32 of KVBLK=64 each).
// Swapped QK^T (A=K, B=Q) with hi/lo split; defer-rescale (thr=8 log2);
// per-lane partial row-sums (no cross-lane shuffles in common path);
// split-softmax merge across t2-partners in epilogue.
// ---------------------------------------------------------------------------
__global__ __launch_bounds__(256, 2) void k_attn(
    const u16* __restrict__ Qh, const u16* __restrict__ Ql,
    const u16* __restrict__ Kh, const u16* __restrict__ Kl,
    const u16* __restrict__ Vp, float* __restrict__ O)
{
    __shared__ __align__(16) char lds[49152];  // 2 x (Kh 8K | Kl 8K | Vp 8K)
    const int hw  = blockIdx.x;
    const int b   = hw & 7;        // batch -> XCD pinning
    const int qt  = hw >> 3;       // 0..63
    const int tid = threadIdx.x;
    const int lane = tid & 63;
    const int wv  = tid >> 6;
    const int wq  = wv >> 1;       // Q-half
    const int wt  = wv & 1;        // t2-half
    const int r   = lane & 15;
    const int g   = lane >> 4;

    // Q fragments: rows t1 = qt*64 + wq*32 + rt*16 + r
    bf16x8 qh[2][2], ql[2][2];
#pragma unroll
    for (int rt = 0; rt < 2; ++rt) {
        const int t1 = qt * 64 + wq * 32 + rt * 16 + r;
        const size_t qoff = ((size_t)(b * NTOK + t1)) * 64 + g * 8;
        qh[rt][0] = *(const bf16x8*)(Qh + qoff);
        qh[rt][1] = *(const bf16x8*)(Qh + qoff + 32);
        ql[rt][0] = *(const bf16x8*)(Ql + qoff);
        ql[rt][1] = *(const bf16x8*)(Ql + qoff + 32);
    }

    // K frag LDS offsets: this wave reads st = 2*wt + sti (t2loc = st*16 + r)
    int koff[2][2];
#pragma unroll
    for (int sti = 0; sti < 2; ++sti)
#pragma unroll
        for (int ks = 0; ks < 2; ++ks)
            koff[sti][ks] = ((2*wt + sti)*16 + r) * 128 + (((g + 4*ks) ^ (r & 7)) << 4);
    int voff[4];
#pragma unroll
    for (int cb = 0; cb < 4; ++cb)
        voff[cb] = 16384 + ((cb * 2 + wt) * 64 + lane) * 16;

    const char* gKh = (const char*)(Kh + (size_t)b * NTOK * 64);
    const char* gKl = (const char*)(Kl + (size_t)b * NTOK * 64);
    const char* gVp = (const char*)Vp + (size_t)b * NT64 * 512 * 16;

    auto stage = [&](int T, int buf) {
        char* dst = lds + buf * 24576 + tid * 16;
        const size_t go = (size_t)T * 8192 + tid * 16;
        async_copy16(dst,         gKh + go);
        async_copy16(dst + 4096,  gKh + go + 4096);
        async_copy16(dst + 8192,  gKl + go);
        async_copy16(dst + 12288, gKl + go + 4096);
        async_copy16(dst + 16384, gVp + go);
        async_copy16(dst + 20480, gVp + go + 4096);
    };

    f32x4 oacc[2][4];
#pragma unroll
    for (int rt = 0; rt < 2; ++rt)
#pragma unroll
        for (int cb = 0; cb < 4; ++cb) oacc[rt][cb] = 0.f;
    float mrun[2] = {-1e30f, -1e30f};
    float lpart[2] = {0.f, 0.f};

    stage(0, 0);
    asm volatile("s_waitcnt vmcnt(0)" ::: "memory");
    __syncthreads();
    int cur = 0;

    for (int T = 0; T < NT64; ++T) {
        if (T + 1 < NT64) stage(T + 1, cur ^ 1);

        const char* base = lds + cur * 24576;
        bf16x8 kh[2][2], kl[2][2];
#pragma unroll
        for (int sti = 0; sti < 2; ++sti)
#pragma unroll
            for (int ks = 0; ks < 2; ++ks) {
                kh[sti][ks] = *(const bf16x8*)(base + koff[sti][ks]);
                kl[sti][ks] = *(const bf16x8*)(base + 8192 + koff[sti][ks]);
            }
        bf16x8 vf[4];
#pragma unroll
        for (int cb = 0; cb < 4; ++cb)
            vf[cb] = *(const bf16x8*)(base + voff[cb]);

        // QK^T: 12 independent depth-2 chains
        f32x4 s[2][2];
#pragma unroll
        for (int rt = 0; rt < 2; ++rt)
#pragma unroll
            for (int sti = 0; sti < 2; ++sti) {
                f32x4 sa = 0.f, sb = 0.f, sc = 0.f;
                sa = MFMA(kh[sti][0], qh[rt][0], sa); sa = MFMA(kh[sti][1], qh[rt][1], sa);
                sb = MFMA(kh[sti][0], ql[rt][0], sb); sb = MFMA(kh[sti][1], ql[rt][1], sb);
                sc = MFMA(kl[sti][0], qh[rt][0], sc); sc = MFMA(kl[sti][1], qh[rt][1], sc);
                s[rt][sti] = (sa + sb) + sc;
            }

        // lane-local max per rowtile (8 values each)
        float m8[2];
#pragma unroll
        for (int rt = 0; rt < 2; ++rt) {
            float a = fmaxf(fmaxf(s[rt][0][0], s[rt][0][1]), fmaxf(s[rt][0][2], s[rt][0][3]));
            float c = fmaxf(fmaxf(s[rt][1][0], s[rt][1][1]), fmaxf(s[rt][1][2], s[rt][1][3]));
            m8[rt] = fmaxf(a, c);
        }
        if (__any(m8[0] > mrun[0] + 8.f || m8[1] > mrun[1] + 8.f)) {
            // rare: true rescale with cross-lane row max
#pragma unroll
            for (int rt = 0; rt < 2; ++rt) {
                float mr = fmaxf(m8[rt], __shfl_xor(m8[rt], 16));
                mr = fmaxf(mr, __shfl_xor(mr, 32));
                const float mnew = fmaxf(mrun[rt], mr);
                const float corr = EXP2F(mrun[rt] - mnew);
                lpart[rt] *= corr;
                float c4[4];
#pragma unroll
                for (int i = 0; i < 4; ++i) c4[i] = __shfl(corr, g * 4 + i);
#pragma unroll
                for (int cb = 0; cb < 4; ++cb)
#pragma unroll
                    for (int i = 0; i < 4; ++i) oacc[rt][cb][i] *= c4[i];
                mrun[rt] = mnew;
            }
        }

        bf16x8 pa[2];
#pragma unroll
        for (int rt = 0; rt < 2; ++rt) {
            float p[8];
            float ls = 0.f;
#pragma unroll
            for (int sti = 0; sti < 2; ++sti)
#pragma unroll
                for (int i = 0; i < 4; ++i) {
                    const float pv = EXP2F(s[rt][sti][i] - mrun[rt]);
                    p[sti*4+i] = pv; ls += pv;
                }
            lpart[rt] += ls;
#pragma unroll
            for (int j = 0; j < 8; ++j) pa[rt][j] = (short)f2bf(p[j]);
        }

#pragma unroll
        for (int rt = 0; rt < 2; ++rt)
#pragma unroll
            for (int cb = 0; cb < 4; ++cb)
                oacc[rt][cb] = MFMA(pa[rt], vf[cb], oacc[rt][cb]);

        asm volatile("s_waitcnt vmcnt(0)" ::: "memory");
        __syncthreads();
        cur ^= 1;
    }

    // ---- epilogue: reduce lane partials, merge t2-halves, write O[t][c] ----
    float lsum[2];
#pragma unroll
    for (int rt = 0; rt < 2; ++rt) {
        float v = lpart[rt];
        v += __shfl_xor(v, 16);
        v += __shfl_xor(v, 32);
        lsum[rt] = v;
    }

    float* marr = (float*)lds;           // [wq][wt][rt][16]
    float* larr = (float*)(lds + 512);
    if (lane < 16) {
#pragma unroll
        for (int rt = 0; rt < 2; ++rt) {
            marr[((wq*2 + wt)*2 + rt)*16 + lane] = mrun[rt];
            larr[((wq*2 + wt)*2 + rt)*16 + lane] = lsum[rt];
        }
    }
    __syncthreads();

    float w4[2][4];
#pragma unroll
    for (int rt = 0; rt < 2; ++rt) {
        const float mo = marr[((wq*2 + (wt^1))*2 + rt)*16 + r];
        const float lo_ = larr[((wq*2 + (wt^1))*2 + rt)*16 + r];
        const float mstar = fmaxf(mrun[rt], mo);
        const float f  = EXP2F(mrun[rt] - mstar);
        const float fo = EXP2F(mo - mstar);
        const float lstar = lsum[rt] * f + lo_ * fo;
        const float wsc = f / lstar;
#pragma unroll
        for (int i = 0; i < 4; ++i) w4[rt][i] = __shfl(wsc, g * 4 + i);
    }

    float* otile = (float*)(lds + 1024);  // [wq][32][66]
    if (wt == 0) {
#pragma unroll
        for (int rt = 0; rt < 2; ++rt)
#pragma unroll
            for (int cb = 0; cb < 4; ++cb)
#pragma unroll
                for (int i = 0; i < 4; ++i) {
                    const int tloc = rt*16 + g*4 + i;
                    const int c = cb*16 + r;
                    otile[(wq*32 + tloc)*66 + c] = oacc[rt][cb][i] * w4[rt][i];
                }
    }
    __syncthreads();
    if (wt == 1) {
#pragma unroll
        for (int rt = 0; rt < 2; ++rt)
#pragma unroll
            for (int cb = 0; cb < 4; ++cb)
#pragma unroll
                for (int i = 0; i < 4; ++i) {
                    const int tloc = rt*16 + g*4 + i;
                    const int c = cb*16 + r;
                    const float val = otile[(wq*32 + tloc)*66 + c] + oacc[rt][cb][i] * w4[rt][i];
                    const int trow = qt*64 + wq*32 + tloc;
                    O[((size_t)(b * NTOK + trow)) * 64 + c] = val;
                }
    }
}

// ---------------------------------------------------------------------------
// k4: out projection (fp32) + residual.
// ---------------------------------------------------------------------------
__global__ __launch_bounds__(256) void k_out(
    const float* __restrict__ O, const float* __restrict__ wout, const float* __restrict__ bout,
    const float* __restrict__ x, float* __restrict__ out)
{
    const int blk  = blockIdx.x;
    const int b    = blk >> 6;
    const int tbase = (blk & 63) << 6;
    const int tid  = threadIdx.x;
    const int tl   = tid & 63;
    const int osub = __builtin_amdgcn_readfirstlane(tid >> 6);
    const int t    = tbase + tl;

    float y[64];
    const float* orow = O + ((size_t)(b * NTOK + t)) * 64;
#pragma unroll
    for (int c4 = 0; c4 < 16; ++c4) {
        f32x4 v = *(const f32x4*)(orow + c4 * 4);
        y[c4*4+0] = v[0]; y[c4*4+1] = v[1]; y[c4*4+2] = v[2]; y[c4*4+3] = v[3];
    }
#pragma unroll
    for (int i = 0; i < 16; ++i) {
        const int o = osub * 16 + i;
        float acc = bout[o];
        const float* wr = wout + o * 64;   // uniform per wave -> scalar loads
#pragma unroll
        for (int c = 0; c < 64; ++c) acc = fmaf(wr[c], y[c], acc);
        const size_t xi = (size_t)(b * 64 + o) * NTOK + t;
        out[xi] = acc + x[xi];
    }
}

extern "C" void kernel_launch(void* const* d_in, const int* in_sizes, int n_in,
                              void* d_out, int out_size, void* d_ws, size_t ws_size,
                              hipStream_t stream)
{
    (void)in_sizes; (void)n_in; (void)out_size; (void)ws_size;
    const float* x    = (const float*)d_in[0];
    const float* wqkv = (const float*)d_in[1];
    const float* bqkv = (const float*)d_in[2];
    const float* wout = (const float*)d_in[3];
    const float* bout = (const float*)d_in[4];
    float* out = (float*)d_out;

    char* ws = (char*)d_ws;
    const size_t MB = 1024 * 1024;
    u16* Qh = (u16*)(ws);
    u16* Ql = (u16*)(ws + 4 * MB);
    u16* Kh = (u16*)(ws + 8 * MB);
    u16* Kl = (u16*)(ws + 12 * MB);
    u16* Vp = (u16*)(ws + 16 * MB);
    float* Ob = (float*)(ws + 20 * MB);

    k_qkv<<<512, 256, 0, stream>>>(x, wqkv, bqkv, Qh, Ql, Kh, Kl, Vp);
    k_attn<<<512, 256, 0, stream>>>(Qh, Ql, Kh, Kl, Vp, Ob);
    k_out<<<512, 256, 0, stream>>>(Ob, wout, bout, x, out);
}

// Round 3
// 120.753 us; speedup vs baseline: 1.4841x; 1.1698x over previous
//
#include <hip/hip_runtime.h>
#include <hip/hip_bf16.h>
#include <stdint.h>

typedef unsigned short u16;
typedef __attribute__((ext_vector_type(8))) short bf16x8;
typedef __attribute__((ext_vector_type(4))) float f32x4;
typedef __attribute__((ext_vector_type(4))) unsigned int u32x4;
typedef __attribute__((ext_vector_type(2))) unsigned int u32x2;

#define NTOK 4096
#define NT32 32   // 4096 / 128 t2-tiles

#if __has_builtin(__builtin_amdgcn_exp2f)
#define EXP2F __builtin_amdgcn_exp2f
#else
#define EXP2F exp2f
#endif

__device__ __forceinline__ u16 f2bf(float f) {
    __hip_bfloat16 h = __float2bfloat16(f);
    return *reinterpret_cast<u16*>(&h);
}
__device__ __forceinline__ float bf2f(u16 u) {
    __hip_bfloat16 h = *reinterpret_cast<__hip_bfloat16*>(&u);
    return __bfloat162float(h);
}

__device__ __forceinline__ f32x4 MFMA(bf16x8 a, bf16x8 b, f32x4 c) {
    return __builtin_amdgcn_mfma_f32_16x16x32_bf16(a, b, c, 0, 0, 0);
}

// ---------------------------------------------------------------------------
// k1: QKV projection (fp32) + packing.
// Q: [b][t][c] bf16 hi/lo, pre-scaled by 0.125*log2(e).
// K: single bf16, MFMA-A-fragment order: Kp[b][gg=t>>4][ks][lane][8]
//    elem j = K[gg*16 + (lane&15)][(lane>>4)*8 + j + 32*ks]
// V: MFMA-B-fragment order: Vp[b][T=t2>>7][wt][cb][lane][sti][4]
//    elem jj = V[T*128 + wt*32 + sti*16 + (lane>>4)*4 + jj][cb*16 + (lane&15)]
// ---------------------------------------------------------------------------
__global__ __launch_bounds__(256) void k_qkv(
    const float* __restrict__ x, const float* __restrict__ wqkv, const float* __restrict__ bqkv,
    u16* __restrict__ Qh, u16* __restrict__ Ql,
    u16* __restrict__ Kp, u16* __restrict__ Vp)
{
    __shared__ uint32_t vlds[64 * 33];   // 64 rows x 66 shorts (padded)
    const int blk  = blockIdx.x;
    const int b    = blk >> 6;
    const int tbase = (blk & 63) << 6;
    const int tid  = threadIdx.x;
    const int tl   = tid & 63;
    const int osub = __builtin_amdgcn_readfirstlane(tid >> 6);
    const int t    = tbase + tl;            // batch-local token

    float xc[64];
#pragma unroll
    for (int c = 0; c < 64; ++c)
        xc[c] = x[(size_t)(b * 64 + c) * NTOK + t];

    const float SC = 0.18033688011112042f;  // (1/8) * log2(e)

#pragma unroll
    for (int ch = 0; ch < 6; ++ch) {
        const int o0 = osub * 48 + ch * 8;
        const int arr = o0 >> 6;            // 0=Q, 1=K, 2=V
        float a[8];
#pragma unroll
        for (int j = 0; j < 8; ++j) {
            const int o = o0 + j;
            float acc = bqkv[o];
            const float* wr = wqkv + o * 64;   // uniform per wave -> scalar loads
#pragma unroll
            for (int c = 0; c < 64; ++c) acc = fmaf(wr[c], xc[c], acc);
            a[j] = acc;
        }
        if (arr == 0) {
            // Q: scale, hi/lo split
            u16 h[8], lo[8];
#pragma unroll
            for (int j = 0; j < 8; ++j) {
                const float v = a[j] * SC;
                h[j]  = f2bf(v);
                lo[j] = f2bf(v - bf2f(h[j]));
            }
            u32x4 H, L;
#pragma unroll
            for (int j = 0; j < 4; ++j) {
                H[j] = (uint32_t)h[2*j]  | ((uint32_t)h[2*j+1]  << 16);
                L[j] = (uint32_t)lo[2*j] | ((uint32_t)lo[2*j+1] << 16);
            }
            const int gch = o0 >> 3;        // 0..7
            size_t base = ((size_t)(b * NTOK + t)) * 64 + gch * 8;
            *(u32x4*)(Qh + base) = H;
            *(u32x4*)(Ql + base) = L;
        } else if (arr == 1) {
            // K: single bf16, fragment pack
            u32x4 H;
#pragma unroll
            for (int j = 0; j < 4; ++j)
                H[j] = (uint32_t)f2bf(a[2*j]) | ((uint32_t)f2bf(a[2*j+1]) << 16);
            const int gch = (o0 & 63) >> 3; // 0..7
            const int g   = gch & 3;
            const int ks  = gch >> 2;
            const int lane = (t & 15) + g * 16;
            size_t idx = (size_t)b * 262144 + (((size_t)(t >> 4) * 2 + ks) * 64 + lane) * 8;
            *(u32x4*)(Kp + idx) = H;
        } else {
            // V -> LDS rows
#pragma unroll
            for (int j = 0; j < 4; ++j)
                vlds[tl * 33 + ((o0 & 63) >> 1) + j] =
                    (uint32_t)f2bf(a[2*j]) | ((uint32_t)f2bf(a[2*j+1]) << 16);
        }
    }
    __syncthreads();

    // V fragment pack: block covers t2loc128 = halfb*64 + tl of tile T
    const u16* vl16 = (const u16*)vlds;
    const int T = (blk & 63) >> 1;
    const int halfb = blk & 1;
#pragma unroll
    for (int k = 0; k < 4; ++k) {
        const int u   = k * 256 + tid;
        const int lane = u & 63;
        const int rest = u >> 6;            // 0..15
        const int sti = rest & 1;
        const int cb  = (rest >> 1) & 3;
        const int wtr = rest >> 3;          // 0..1
        const int r2  = lane & 15;
        const int g2  = lane >> 4;
        u16 e[4];
#pragma unroll
        for (int jj = 0; jj < 4; ++jj)
            e[jj] = vl16[(wtr * 32 + sti * 16 + g2 * 4 + jj) * 66 + cb * 16 + r2];
        u32x2 w2;
        w2[0] = (uint32_t)e[0] | ((uint32_t)e[1] << 16);
        w2[1] = (uint32_t)e[2] | ((uint32_t)e[3] << 16);
        size_t idx = (size_t)b * 262144 +
                     ((((size_t)T * 4 + (halfb * 2 + wtr)) * 4 + cb) * 64 + lane) * 8 + sti * 4;
        *(u32x2*)(Vp + idx) = w2;
    }
}

// ---------------------------------------------------------------------------
// k3: flash attention, REGISTER-ONLY main loop (no LDS, no barriers).
// grid 512 (8 batches x 64 Q-tiles of 64 rows), block 256 = 4 waves.
// Each wave owns a 32-t2 slice of each 128-t2 tile for QK^T AND PV;
// 4-way split-softmax merged once in the epilogue via LDS.
// S = Kh*(Qh+Ql): K single bf16 (halves K traffic), Q hi/lo (free).
// ---------------------------------------------------------------------------
__global__ __launch_bounds__(256, 2) void k_attn(
    const u16* __restrict__ Qh, const u16* __restrict__ Ql,
    const u16* __restrict__ Kp, const u16* __restrict__ Vp, float* __restrict__ O)
{
    __shared__ float marr[4][4][16];
    __shared__ float larr[4][4][16];
    __shared__ float otile[64][66];
    const int hw  = blockIdx.x;
    const int b   = hw & 7;        // batch -> XCD pinning
    const int qt  = hw >> 3;       // 0..63
    const int tid = threadIdx.x;
    const int lane = tid & 63;
    const int wt  = tid >> 6;      // wave = t2 sub-slice
    const int r   = lane & 15;
    const int g   = lane >> 4;

    // Q fragments (B operand), rows t1 = qt*64 + rt*16 + r
    bf16x8 qh[4][2], ql[4][2];
#pragma unroll
    for (int rt = 0; rt < 4; ++rt) {
        const int t1 = qt * 64 + rt * 16 + r;
        const size_t qoff = ((size_t)(b * NTOK + t1)) * 64 + g * 8;
        qh[rt][0] = *(const bf16x8*)(Qh + qoff);
        qh[rt][1] = *(const bf16x8*)(Qh + qoff + 32);
        ql[rt][0] = *(const bf16x8*)(Ql + qoff);
        ql[rt][1] = *(const bf16x8*)(Ql + qoff + 32);
    }

    const u16* Kb = Kp + (size_t)b * 262144;
    const u16* Vb = Vp + (size_t)b * 262144;

    f32x4 oacc[4][4];
#pragma unroll
    for (int rt = 0; rt < 4; ++rt)
#pragma unroll
        for (int cb = 0; cb < 4; ++cb) oacc[rt][cb] = 0.f;
    float mrun[4] = {-1e30f, -1e30f, -1e30f, -1e30f};
    float lpart[4] = {0.f, 0.f, 0.f, 0.f};

    // K fragment pointers: tile T, subtile sti, chunk ks ->
    //   Kb + (((T*8 + wt*2 + sti)*2 + ks)*64 + lane)*8
    bf16x8 kc[2][2];
#pragma unroll
    for (int sti = 0; sti < 2; ++sti)
#pragma unroll
        for (int ks = 0; ks < 2; ++ks)
            kc[sti][ks] = *(const bf16x8*)(Kb + ((((size_t)0 * 8 + wt * 2 + sti) * 2 + ks) * 64 + lane) * 8);

    for (int T = 0; T < NT32; ++T) {
        // V fragments for this tile (used late -> latency hidden by QK)
        bf16x8 vf[4];
#pragma unroll
        for (int cb = 0; cb < 4; ++cb)
            vf[cb] = *(const bf16x8*)(Vb + ((((size_t)T * 4 + wt) * 4 + cb) * 64 + lane) * 8);

        // prefetch next tile's K
        const int Tn = (T + 1 < NT32) ? T + 1 : T;
        bf16x8 kn[2][2];
#pragma unroll
        for (int sti = 0; sti < 2; ++sti)
#pragma unroll
            for (int ks = 0; ks < 2; ++ks)
                kn[sti][ks] = *(const bf16x8*)(Kb + ((((size_t)Tn * 8 + wt * 2 + sti) * 2 + ks) * 64 + lane) * 8);

        // QK^T: S^T[t2][t1], t2 = T*128 + wt*32 + sti*16 + g*4 + i, t1 = rt*16 + r
        f32x4 s[4][2];
#pragma unroll
        for (int rt = 0; rt < 4; ++rt)
#pragma unroll
            for (int sti = 0; sti < 2; ++sti) {
                f32x4 acc = 0.f;
                acc = MFMA(kc[sti][0], qh[rt][0], acc);
                acc = MFMA(kc[sti][1], qh[rt][1], acc);
                acc = MFMA(kc[sti][0], ql[rt][0], acc);
                acc = MFMA(kc[sti][1], ql[rt][1], acc);
                s[rt][sti] = acc;
            }

        // lane-local max; deferred rescale (thr = 8 in log2 units)
        float m8[4];
#pragma unroll
        for (int rt = 0; rt < 4; ++rt) {
            float a = fmaxf(fmaxf(s[rt][0][0], s[rt][0][1]), fmaxf(s[rt][0][2], s[rt][0][3]));
            float c = fmaxf(fmaxf(s[rt][1][0], s[rt][1][1]), fmaxf(s[rt][1][2], s[rt][1][3]));
            m8[rt] = fmaxf(a, c);
        }
        const bool need = (m8[0] > mrun[0] + 8.f) || (m8[1] > mrun[1] + 8.f) ||
                          (m8[2] > mrun[2] + 8.f) || (m8[3] > mrun[3] + 8.f);
        if (__any(need)) {
#pragma unroll
            for (int rt = 0; rt < 4; ++rt) {
                float mr = fmaxf(m8[rt], __shfl_xor(m8[rt], 16));
                mr = fmaxf(mr, __shfl_xor(mr, 32));
                const float mnew = fmaxf(mrun[rt], mr);
                const float corr = EXP2F(mrun[rt] - mnew);
                lpart[rt] *= corr;
                float c4[4];
#pragma unroll
                for (int i = 0; i < 4; ++i) c4[i] = __shfl(corr, g * 4 + i);
#pragma unroll
                for (int cb = 0; cb < 4; ++cb)
#pragma unroll
                    for (int i = 0; i < 4; ++i) oacc[rt][cb][i] *= c4[i];
                mrun[rt] = mnew;
            }
        }

        // P = exp2(S - m), PV
#pragma unroll
        for (int rt = 0; rt < 4; ++rt) {
            float p[8];
            float ls = 0.f;
#pragma unroll
            for (int sti = 0; sti < 2; ++sti)
#pragma unroll
                for (int i = 0; i < 4; ++i) {
                    const float pv = EXP2F(s[rt][sti][i] - mrun[rt]);
                    p[sti*4 + i] = pv; ls += pv;
                }
            lpart[rt] += ls;
            bf16x8 pa;
#pragma unroll
            for (int j = 0; j < 8; ++j) pa[j] = (short)f2bf(p[j]);
#pragma unroll
            for (int cb = 0; cb < 4; ++cb)
                oacc[rt][cb] = MFMA(pa, vf[cb], oacc[rt][cb]);
        }

        // rotate K prefetch buffer
#pragma unroll
        for (int sti = 0; sti < 2; ++sti)
#pragma unroll
            for (int ks = 0; ks < 2; ++ks)
                kc[sti][ks] = kn[sti][ks];
    }

    // ---- epilogue: 4-way split-softmax merge across waves ----
    float lsum[4];
#pragma unroll
    for (int rt = 0; rt < 4; ++rt) {
        float v = lpart[rt];
        v += __shfl_xor(v, 16);
        v += __shfl_xor(v, 32);
        lsum[rt] = v;
    }
    if (lane < 16) {
#pragma unroll
        for (int rt = 0; rt < 4; ++rt) {
            marr[wt][rt][lane] = mrun[rt];
            larr[wt][rt][lane] = lsum[rt];
        }
    }
    __syncthreads();

    float w4[4][4];
#pragma unroll
    for (int rt = 0; rt < 4; ++rt) {
        const float m0 = marr[0][rt][r], m1 = marr[1][rt][r];
        const float m2 = marr[2][rt][r], m3 = marr[3][rt][r];
        const float mstar = fmaxf(fmaxf(m0, m1), fmaxf(m2, m3));
        const float lstar = larr[0][rt][r] * EXP2F(m0 - mstar)
                          + larr[1][rt][r] * EXP2F(m1 - mstar)
                          + larr[2][rt][r] * EXP2F(m2 - mstar)
                          + larr[3][rt][r] * EXP2F(m3 - mstar);
        const float wsc = EXP2F(mrun[rt] - mstar) / lstar;
#pragma unroll
        for (int i = 0; i < 4; ++i) w4[rt][i] = __shfl(wsc, g * 4 + i);
    }

    // staged accumulation: wt0 writes, wt1/2 add, wt3 adds + stores global
    if (wt == 0) {
#pragma unroll
        for (int rt = 0; rt < 4; ++rt)
#pragma unroll
            for (int cb = 0; cb < 4; ++cb)
#pragma unroll
                for (int i = 0; i < 4; ++i)
                    otile[rt*16 + g*4 + i][cb*16 + r] = oacc[rt][cb][i] * w4[rt][i];
    }
    __syncthreads();
    if (wt == 1) {
#pragma unroll
        for (int rt = 0; rt < 4; ++rt)
#pragma unroll
            for (int cb = 0; cb < 4; ++cb)
#pragma unroll
                for (int i = 0; i < 4; ++i)
                    otile[rt*16 + g*4 + i][cb*16 + r] += oacc[rt][cb][i] * w4[rt][i];
    }
    __syncthreads();
    if (wt == 2) {
#pragma unroll
        for (int rt = 0; rt < 4; ++rt)
#pragma unroll
            for (int cb = 0; cb < 4; ++cb)
#pragma unroll
                for (int i = 0; i < 4; ++i)
                    otile[rt*16 + g*4 + i][cb*16 + r] += oacc[rt][cb][i] * w4[rt][i];
    }
    __syncthreads();
    if (wt == 3) {
#pragma unroll
        for (int rt = 0; rt < 4; ++rt)
#pragma unroll
            for (int cb = 0; cb < 4; ++cb)
#pragma unroll
                for (int i = 0; i < 4; ++i) {
                    const int row = rt*16 + g*4 + i;
                    const float val = otile[row][cb*16 + r] + oacc[rt][cb][i] * w4[rt][i];
                    O[((size_t)(b * NTOK + qt*64 + row)) * 64 + cb*16 + r] = val;
                }
    }
}

// ---------------------------------------------------------------------------
// k4: out projection (fp32) + residual.
// ---------------------------------------------------------------------------
__global__ __launch_bounds__(256) void k_out(
    const float* __restrict__ O, const float* __restrict__ wout, const float* __restrict__ bout,
    const float* __restrict__ x, float* __restrict__ out)
{
    const int blk  = blockIdx.x;
    const int b    = blk >> 6;
    const int tbase = (blk & 63) << 6;
    const int tid  = threadIdx.x;
    const int tl   = tid & 63;
    const int osub = __builtin_amdgcn_readfirstlane(tid >> 6);
    const int t    = tbase + tl;

    float y[64];
    const float* orow = O + ((size_t)(b * NTOK + t)) * 64;
#pragma unroll
    for (int c4 = 0; c4 < 16; ++c4) {
        f32x4 v = *(const f32x4*)(orow + c4 * 4);
        y[c4*4+0] = v[0]; y[c4*4+1] = v[1]; y[c4*4+2] = v[2]; y[c4*4+3] = v[3];
    }
#pragma unroll
    for (int i = 0; i < 16; ++i) {
        const int o = osub * 16 + i;
        float acc = bout[o];
        const float* wr = wout + o * 64;   // uniform per wave -> scalar loads
#pragma unroll
        for (int c = 0; c < 64; ++c) acc = fmaf(wr[c], y[c], acc);
        const size_t xi = (size_t)(b * 64 + o) * NTOK + t;
        out[xi] = acc + x[xi];
    }
}

extern "C" void kernel_launch(void* const* d_in, const int* in_sizes, int n_in,
                              void* d_out, int out_size, void* d_ws, size_t ws_size,
                              hipStream_t stream)
{
    (void)in_sizes; (void)n_in; (void)out_size; (void)ws_size;
    const float* x    = (const float*)d_in[0];
    const float* wqkv = (const float*)d_in[1];
    const float* bqkv = (const float*)d_in[2];
    const float* wout = (const float*)d_in[3];
    const float* bout = (const float*)d_in[4];
    float* out = (float*)d_out;

    char* ws = (char*)d_ws;
    const size_t MB = 1024 * 1024;
    u16* Qh = (u16*)(ws);
    u16* Ql = (u16*)(ws + 4 * MB);
    u16* Kp = (u16*)(ws + 8 * MB);
    u16* Vp = (u16*)(ws + 12 * MB);
    float* Ob = (float*)(ws + 16 * MB);

    k_qkv<<<512, 256, 0, stream>>>(x, wqkv, bqkv, Qh, Ql, Kp, Vp);
    k_attn<<<512, 256, 0, stream>>>(Qh, Ql, Kp, Vp, Ob);
    k_out<<<512, 256, 0, stream>>>(Ob, wout, bout, x, out);
}

// Round 4
// 63.201 us; speedup vs baseline: 2.8356x; 1.9106x over previous
//
#include <hip/hip_runtime.h>
#include <hip/hip_bf16.h>
#include <stdint.h>

typedef unsigned short u16;
typedef __attribute__((ext_vector_type(8))) short bf16x8;
typedef __attribute__((ext_vector_type(4))) float f32x4;
typedef __attribute__((ext_vector_type(2))) float f32x2;
typedef __attribute__((ext_vector_type(4))) unsigned int u32x4;
typedef __attribute__((ext_vector_type(2))) unsigned int u32x2;

#define NTOK 4096
#define NT32 32   // 4096 / 128 t2-tiles

#if __has_builtin(__builtin_amdgcn_exp2f)
#define EXP2F __builtin_amdgcn_exp2f
#else
#define EXP2F exp2f
#endif

__device__ __forceinline__ f32x4 MFMA(bf16x8 a, bf16x8 b, f32x4 c) {
    return __builtin_amdgcn_mfma_f32_16x16x32_bf16(a, b, c, 0, 0, 0);
}

// packed f32->bf16 (D.lo = bf16(a), D.hi = bf16(b))
__device__ __forceinline__ uint32_t pk_bf16(float a, float b) {
    uint32_t d;
    asm("v_cvt_pk_bf16_f32 %0, %1, %2" : "=v"(d) : "v"(a), "v"(b));
    return d;
}

// truncation hi/lo split of 8 floats into two bf16x8 fragments (hi + lo ~ 16-bit mantissa)
__device__ __forceinline__ void hilo_pack8(const float* v, bf16x8* h, bf16x8* l) {
    union { uint32_t u[4]; bf16x8 b; } H, L;
#pragma unroll
    for (int m = 0; m < 4; ++m) {
        const uint32_t ua = __float_as_uint(v[2*m]);
        const uint32_t ub = __float_as_uint(v[2*m+1]);
        const float la = v[2*m]   - __uint_as_float(ua & 0xffff0000u);
        const float lb = v[2*m+1] - __uint_as_float(ub & 0xffff0000u);
        H.u[m] = (ua >> 16) | (ub & 0xffff0000u);
        L.u[m] = (__float_as_uint(la) >> 16) | (__float_as_uint(lb) & 0xffff0000u);
    }
    *h = H.b; *l = L.b;
}

// ---------------------------------------------------------------------------
// k_qkv: QKV projection via MFMA (w,x hi/lo 3-term), then repack through LDS.
// Block = (batch b, 64-token tile). 256 thr = 4 waves; wave wv owns 48 outputs.
// Outputs:
//  Qp: [b][t][c] bf16, pre-scaled by 0.125*log2(e)
//  Kp: frag order: b*262144 + ((t>>4)*2 + ks)*512 + (c8&3)*128 + (t&15)*8 + (c&7)
//  Vp: frag order: b*262144 + (((t2>>7)*4 + (t2>>5)&3)*4 + c>>4)*512
//                   + (((t2>>2)&3)*16 + (c&15))*8 + ((t2>>4)&1)*4 + (t2&3)
// ---------------------------------------------------------------------------
__global__ __launch_bounds__(256) void k_qkv(
    const float* __restrict__ x, const float* __restrict__ wqkv, const float* __restrict__ bqkv,
    u16* __restrict__ Qp, u16* __restrict__ Kp, u16* __restrict__ Vp)
{
    __shared__ float qt_lds[64 * 194];   // qkvT[t][o], stride 194 (8B-aligned rows, 2-way banks)
    const int blk = blockIdx.x;
    const int b   = blk >> 6;
    const int tb  = (blk & 63) << 6;
    const int tid = threadIdx.x;
    const int lane = tid & 63;
    const int wv  = __builtin_amdgcn_readfirstlane(tid >> 6);
    const int r   = lane & 15;
    const int g   = lane >> 4;
    const int o0  = wv * 48;

    // w-fragments (A operand): lane holds w[o0+oi*16+r][c = ks*32 + g*8 + j], hi/lo
    bf16x8 wh[3][2], wl[3][2];
#pragma unroll
    for (int oi = 0; oi < 3; ++oi)
#pragma unroll
        for (int ks = 0; ks < 2; ++ks) {
            const float* wp = wqkv + (size_t)(o0 + oi*16 + r) * 64 + ks*32 + g*8;
            float wv8[8];
            *(f32x4*)(wv8)     = *(const f32x4*)(wp);
            *(f32x4*)(wv8 + 4) = *(const f32x4*)(wp + 4);
            hilo_pack8(wv8, &wh[oi][ks], &wl[oi][ks]);
        }

    f32x4 acc[3][4];
#pragma unroll
    for (int oi = 0; oi < 3; ++oi)
#pragma unroll
        for (int tt = 0; tt < 4; ++tt) acc[oi][tt] = 0.f;

#pragma unroll
    for (int tt = 0; tt < 4; ++tt) {
        // x-fragments (B operand) straight from global: x[t = tb+tt*16+r][c]
        bf16x8 xh[2], xl[2];
#pragma unroll
        for (int ks = 0; ks < 2; ++ks) {
            float xv[8];
#pragma unroll
            for (int j = 0; j < 8; ++j)
                xv[j] = x[(size_t)(b*64 + ks*32 + g*8 + j) * NTOK + tb + tt*16 + r];
            hilo_pack8(xv, &xh[ks], &xl[ks]);
        }
#pragma unroll
        for (int oi = 0; oi < 3; ++oi) {
            f32x4 a = acc[oi][tt];
            a = MFMA(wh[oi][0], xh[0], a);
            a = MFMA(wh[oi][1], xh[1], a);
            a = MFMA(wl[oi][0], xh[0], a);
            a = MFMA(wl[oi][1], xh[1], a);
            a = MFMA(wh[oi][0], xl[0], a);
            a = MFMA(wh[oi][1], xl[1], a);
            acc[oi][tt] = a;
        }
    }

    // scatter accumulators to qkvT[t][o]  (lane holds o = o0+oi*16+g*4+i, t = tt*16+r)
#pragma unroll
    for (int oi = 0; oi < 3; ++oi)
#pragma unroll
        for (int tt = 0; tt < 4; ++tt)
#pragma unroll
            for (int i = 0; i < 4; ++i)
                qt_lds[(tt*16 + r) * 194 + o0 + oi*16 + g*4 + i] = acc[oi][tt][i];
    __syncthreads();

    const float SC = 0.18033688011112042f;  // (1/8) * log2(e)

    // ---- Q pack: thread covers (t = tid>>2, c0 = (tid&3)*16) ----
    {
        const int t = tid >> 2, c0 = (tid & 3) * 16;
        float v[16], bq[16];
#pragma unroll
        for (int m = 0; m < 8; ++m)
            *(f32x2*)(v + 2*m) = *(const f32x2*)&qt_lds[t*194 + c0 + 2*m];
#pragma unroll
        for (int m = 0; m < 4; ++m)
            *(f32x4*)(bq + 4*m) = *(const f32x4*)(bqkv + c0 + 4*m);
        u32x4 P0, P1;
#pragma unroll
        for (int m = 0; m < 4; ++m) {
            P0[m] = pk_bf16((v[2*m]   + bq[2*m]  ) * SC, (v[2*m+1] + bq[2*m+1]) * SC);
            P1[m] = pk_bf16((v[8+2*m] + bq[8+2*m]) * SC, (v[9+2*m] + bq[9+2*m]) * SC);
        }
        size_t base = ((size_t)(b * NTOK + tb + t)) * 64 + c0;
        *(u32x4*)(Qp + base)     = P0;
        *(u32x4*)(Qp + base + 8) = P1;
    }

    // ---- K pack: 2 units/thread; unit u = (t = u>>3, ks = (u>>2)&1, gk = u&3) ----
#pragma unroll
    for (int uu = 0; uu < 2; ++uu) {
        const int u  = tid * 2 + uu;
        const int t  = u >> 3;
        const int ks = (u >> 2) & 1;
        const int gk = u & 3;
        const int cb0 = 64 + ks*32 + gk*8;
        float v[8];
#pragma unroll
        for (int m = 0; m < 4; ++m)
            *(f32x2*)(v + 2*m) = *(const f32x2*)&qt_lds[t*194 + cb0 + 2*m];
        u32x4 P;
#pragma unroll
        for (int m = 0; m < 4; ++m)
            P[m] = pk_bf16(v[2*m] + bqkv[cb0 + 2*m], v[2*m+1] + bqkv[cb0 + 2*m+1]);
        const int tg = tb + t;
        size_t kbase = (size_t)b * 262144 + ((size_t)(tg >> 4) * 2 + ks) * 512 + gk*128 + (t & 15) * 8;
        *(u32x4*)(Kp + kbase) = P;
    }

    // ---- V pack: 4 units/thread; unit vu = (tq = vu>>6, cb = (vu>>4)&3, r2 = vu&15) ----
    {
        const int cb = (tid >> 4) & 3;
        const int r2 = tid & 15;
        const float bv = bqkv[128 + cb*16 + r2];
        const int T = (blk & 63) >> 1;         // 128-token tile index
        const int halfb = blk & 1;
#pragma unroll
        for (int m = 0; m < 4; ++m) {
            const int tq = m * 4 + (tid >> 6);  // 0..15
            float v[4];
#pragma unroll
            for (int jj = 0; jj < 4; ++jj)
                v[jj] = qt_lds[(tq*4 + jj)*194 + 128 + cb*16 + r2] + bv;
            const int t = tq * 4;               // block-local token base of quad
            const int wtr = halfb*2 + (t >> 5);
            const int sti = (t >> 4) & 1;
            const int g2  = (t >> 2) & 3;
            u32x2 W;
            W[0] = pk_bf16(v[0], v[1]);
            W[1] = pk_bf16(v[2], v[3]);
            size_t vbase = (size_t)b * 262144 +
                           (((size_t)T * 4 + wtr) * 4 + cb) * 512 + (g2*16 + r2) * 8 + sti * 4;
            *(u32x2*)(Vp + vbase) = W;
        }
    }
}

// ---------------------------------------------------------------------------
// k_attn: flash attention, register-only main loop (no LDS, NO barriers),
// fused out-projection + residual in the epilogue.
// grid 512 (8 batches x 64 Q-tiles of 64 rows), block 256 = 4 waves;
// wave wt owns a 32-t2 slice of each 128-t2 tile; 4-way split-softmax merge.
// ---------------------------------------------------------------------------
__global__ __launch_bounds__(256, 2) void k_attn(
    const u16* __restrict__ Qp, const u16* __restrict__ Kp, const u16* __restrict__ Vp,
    const float* __restrict__ wout, const float* __restrict__ bout,
    const float* __restrict__ x, float* __restrict__ out)
{
    __shared__ float marr[4][4][16];
    __shared__ float larr[4][4][16];
    __shared__ float otbuf[2][64 * 67];
    const int hw  = blockIdx.x;
    const int b   = hw & 7;        // batch -> XCD pinning
    const int qt  = hw >> 3;       // 0..63
    const int tid = threadIdx.x;
    const int lane = tid & 63;
    const int wt  = tid >> 6;
    const int r   = lane & 15;
    const int g   = lane >> 4;

    // Q fragments (B operand), rows t1 = qt*64 + rt*16 + r
    bf16x8 qh[4][2];
#pragma unroll
    for (int rt = 0; rt < 4; ++rt) {
        const int t1 = qt * 64 + rt * 16 + r;
        const size_t qoff = ((size_t)(b * NTOK + t1)) * 64 + g * 8;
        qh[rt][0] = *(const bf16x8*)(Qp + qoff);
        qh[rt][1] = *(const bf16x8*)(Qp + qoff + 32);
    }

    const u16* Kb = Kp + (size_t)b * 262144;
    const u16* Vb = Vp + (size_t)b * 262144;

    f32x4 oacc[4][4];
#pragma unroll
    for (int rt = 0; rt < 4; ++rt)
#pragma unroll
        for (int cb = 0; cb < 4; ++cb) oacc[rt][cb] = 0.f;
    float mrun[4] = {-1e30f, -1e30f, -1e30f, -1e30f};
    float lpart[4] = {0.f, 0.f, 0.f, 0.f};

    bf16x8 kc[2][2];
#pragma unroll
    for (int sti = 0; sti < 2; ++sti)
#pragma unroll
        for (int ks = 0; ks < 2; ++ks)
            kc[sti][ks] = *(const bf16x8*)(Kb + ((((size_t)0 + wt*2 + sti) * 2 + ks) * 64 + lane) * 8);

    for (int T = 0; T < NT32; ++T) {
        bf16x8 vf[4];
#pragma unroll
        for (int cb = 0; cb < 4; ++cb)
            vf[cb] = *(const bf16x8*)(Vb + ((((size_t)T * 4 + wt) * 4 + cb) * 64 + lane) * 8);

        const int Tn = (T + 1 < NT32) ? T + 1 : T;
        bf16x8 kn[2][2];
#pragma unroll
        for (int sti = 0; sti < 2; ++sti)
#pragma unroll
            for (int ks = 0; ks < 2; ++ks)
                kn[sti][ks] = *(const bf16x8*)(Kb + ((((size_t)Tn * 8 + wt*2 + sti) * 2 + ks) * 64 + lane) * 8);

        // QK^T: 8 independent depth-2 MFMA chains
        f32x4 s[4][2];
#pragma unroll
        for (int rt = 0; rt < 4; ++rt)
#pragma unroll
            for (int sti = 0; sti < 2; ++sti) {
                f32x4 a = 0.f;
                a = MFMA(kc[sti][0], qh[rt][0], a);
                a = MFMA(kc[sti][1], qh[rt][1], a);
                s[rt][sti] = a;
            }

        float m8[4];
#pragma unroll
        for (int rt = 0; rt < 4; ++rt) {
            float a = fmaxf(fmaxf(s[rt][0][0], s[rt][0][1]), fmaxf(s[rt][0][2], s[rt][0][3]));
            float c = fmaxf(fmaxf(s[rt][1][0], s[rt][1][1]), fmaxf(s[rt][1][2], s[rt][1][3]));
            m8[rt] = fmaxf(a, c);
        }
        const bool need = (m8[0] > mrun[0] + 8.f) || (m8[1] > mrun[1] + 8.f) ||
                          (m8[2] > mrun[2] + 8.f) || (m8[3] > mrun[3] + 8.f);
        if (__any(need)) {
#pragma unroll
            for (int rt = 0; rt < 4; ++rt) {
                float mr = fmaxf(m8[rt], __shfl_xor(m8[rt], 16));
                mr = fmaxf(mr, __shfl_xor(mr, 32));
                const float mnew = fmaxf(mrun[rt], mr);
                const float corr = EXP2F(mrun[rt] - mnew);
                lpart[rt] *= corr;
                float c4[4];
#pragma unroll
                for (int i = 0; i < 4; ++i) c4[i] = __shfl(corr, g * 4 + i);
#pragma unroll
                for (int cb = 0; cb < 4; ++cb)
#pragma unroll
                    for (int i = 0; i < 4; ++i) oacc[rt][cb][i] *= c4[i];
                mrun[rt] = mnew;
            }
        }

#pragma unroll
        for (int rt = 0; rt < 4; ++rt) {
            float p[8];
            float ls = 0.f;
#pragma unroll
            for (int sti = 0; sti < 2; ++sti)
#pragma unroll
                for (int i = 0; i < 4; ++i) {
                    const float pv = EXP2F(s[rt][sti][i] - mrun[rt]);
                    p[sti*4 + i] = pv; ls += pv;
                }
            lpart[rt] += ls;
            union { uint32_t u[4]; bf16x8 b; } PA;
#pragma unroll
            for (int m = 0; m < 4; ++m) PA.u[m] = pk_bf16(p[2*m], p[2*m+1]);
#pragma unroll
            for (int cb = 0; cb < 4; ++cb)
                oacc[rt][cb] = MFMA(PA.b, vf[cb], oacc[rt][cb]);
        }

#pragma unroll
        for (int sti = 0; sti < 2; ++sti)
#pragma unroll
            for (int ks = 0; ks < 2; ++ks)
                kc[sti][ks] = kn[sti][ks];
    }

    // ---- epilogue: 4-way split-softmax merge ----
    float lsum[4];
#pragma unroll
    for (int rt = 0; rt < 4; ++rt) {
        float v = lpart[rt];
        v += __shfl_xor(v, 16);
        v += __shfl_xor(v, 32);
        lsum[rt] = v;
    }
    if (lane < 16) {
#pragma unroll
        for (int rt = 0; rt < 4; ++rt) {
            marr[wt][rt][lane] = mrun[rt];
            larr[wt][rt][lane] = lsum[rt];
        }
    }
    __syncthreads();

    float w4[4][4];
#pragma unroll
    for (int rt = 0; rt < 4; ++rt) {
        const float m0 = marr[0][rt][r], m1 = marr[1][rt][r];
        const float m2 = marr[2][rt][r], m3 = marr[3][rt][r];
        const float mstar = fmaxf(fmaxf(m0, m1), fmaxf(m2, m3));
        const float lstar = larr[0][rt][r] * EXP2F(m0 - mstar)
                          + larr[1][rt][r] * EXP2F(m1 - mstar)
                          + larr[2][rt][r] * EXP2F(m2 - mstar)
                          + larr[3][rt][r] * EXP2F(m3 - mstar);
        const float wsc = EXP2F(mrun[rt] - mstar) / lstar;
#pragma unroll
        for (int i = 0; i < 4; ++i) w4[rt][i] = __shfl(wsc, g * 4 + i);
    }

    // accumulate O tile into LDS: waves 0/1 write two halves, waves 2/3 add
    if (wt < 2) {
        float* ob = otbuf[wt];
#pragma unroll
        for (int rt = 0; rt < 4; ++rt)
#pragma unroll
            for (int cb = 0; cb < 4; ++cb)
#pragma unroll
                for (int i = 0; i < 4; ++i)
                    ob[(rt*16 + g*4 + i)*67 + cb*16 + r] = oacc[rt][cb][i] * w4[rt][i];
    }
    __syncthreads();
    if (wt >= 2) {
        float* ob = otbuf[wt - 2];
#pragma unroll
        for (int rt = 0; rt < 4; ++rt)
#pragma unroll
            for (int cb = 0; cb < 4; ++cb)
#pragma unroll
                for (int i = 0; i < 4; ++i)
                    ob[(rt*16 + g*4 + i)*67 + cb*16 + r] += oacc[rt][cb][i] * w4[rt][i];
    }
    __syncthreads();

    // ---- fused out-projection + bias + residual ----
    // wave wt handles block-local tokens wt*16 + r (B-frag rows)
    bf16x8 oh[2], ol[2];
#pragma unroll
    for (int ks = 0; ks < 2; ++ks) {
        float ov[8];
#pragma unroll
        for (int j = 0; j < 8; ++j) {
            const int idx = (wt*16 + r)*67 + ks*32 + g*8 + j;
            ov[j] = otbuf[0][idx] + otbuf[1][idx];
        }
        hilo_pack8(ov, &oh[ks], &ol[ks]);
    }
    f32x4 acc2[4];
#pragma unroll
    for (int ot = 0; ot < 4; ++ot) {
        bf16x8 wh2[2], wl2[2];
#pragma unroll
        for (int ks = 0; ks < 2; ++ks) {
            const float* wp = wout + (size_t)(ot*16 + r) * 64 + ks*32 + g*8;
            float wv8[8];
            *(f32x4*)(wv8)     = *(const f32x4*)(wp);
            *(f32x4*)(wv8 + 4) = *(const f32x4*)(wp + 4);
            hilo_pack8(wv8, &wh2[ks], &wl2[ks]);
        }
        f32x4 a = 0.f;
        a = MFMA(wh2[0], oh[0], a);
        a = MFMA(wh2[1], oh[1], a);
        a = MFMA(wl2[0], oh[0], a);
        a = MFMA(wl2[1], oh[1], a);
        a = MFMA(wh2[0], ol[0], a);
        a = MFMA(wh2[1], ol[1], a);
        acc2[ot] = a;
    }
#pragma unroll
    for (int ot = 0; ot < 4; ++ot)
#pragma unroll
        for (int i = 0; i < 4; ++i) {
            const int oo = ot*16 + g*4 + i;
            const size_t xi = ((size_t)(b*64 + oo)) * NTOK + qt*64 + wt*16 + r;
            out[xi] = acc2[ot][i] + bout[oo] + x[xi];
        }
}

extern "C" void kernel_launch(void* const* d_in, const int* in_sizes, int n_in,
                              void* d_out, int out_size, void* d_ws, size_t ws_size,
                              hipStream_t stream)
{
    (void)in_sizes; (void)n_in; (void)out_size; (void)ws_size;
    const float* x    = (const float*)d_in[0];
    const float* wqkv = (const float*)d_in[1];
    const float* bqkv = (const float*)d_in[2];
    const float* wout = (const float*)d_in[3];
    const float* bout = (const float*)d_in[4];
    float* out = (float*)d_out;

    char* ws = (char*)d_ws;
    const size_t MB = 1024 * 1024;
    u16* Qp = (u16*)(ws);
    u16* Kp = (u16*)(ws + 4 * MB);
    u16* Vp = (u16*)(ws + 8 * MB);

    k_qkv<<<512, 256, 0, stream>>>(x, wqkv, bqkv, Qp, Kp, Vp);
    k_attn<<<512, 256, 0, stream>>>(Qp, Kp, Vp, wout, bout, x, out);
}